// Round 10
// baseline (136.365 us; speedup 1.0000x reference)
//
#include <hip/hip_runtime.h>
#include <math.h>

#define L_    4096
#define PS_   16
#define STR_  8
#define PC_   511   // (4096-16)/8 + 1
#define HID_  64
#define NBLK_ 2048  // B*C

typedef __bf16 bf16x8 __attribute__((ext_vector_type(8)));
typedef float  f32x4  __attribute__((ext_vector_type(4)));

// gelu tanh-form: x * sigmoid(2c(x + 0.044715 x^3)); |err| <= ~5e-4.
__device__ __forceinline__ float gelu_fast(float x) {
    float u = x * x;
    float t = fmaf(u, 0.10294294f, 2.3022082f);   // 2c·log2(e), pre-scaled
    float a = x * t;
    float e = __builtin_amdgcn_exp2f(a);
    float r = __builtin_amdgcn_rcpf(e + 1.0f);
    return fmaf(-x, r, x);                         // x*(1-r)
}

__global__ __launch_bounds__(256, 4) void depatch_kernel(
    const float* __restrict__ X,
    const float* __restrict__ W1,
    const float* __restrict__ b1,
    const float* __restrict__ W2,
    const float* __restrict__ b2,
    float* __restrict__ out)
{
    // single bf16 row: MFMA B-frags AND sampling. 8.3 KB -> 8 blocks/CU (grid-capped).
    __shared__ __attribute__((aligned(16))) __bf16 s_rowh[L_ + 32];

    const int tid = threadIdx.x;
    const int bc  = blockIdx.x;
    const float* xrow = X + (size_t)bc * L_;

    {
        const float4* src4 = reinterpret_cast<const float4*>(xrow);
        #pragma unroll
        for (int i = 0; i < 4; ++i) {
            float4 v = src4[tid + 256 * i];
            union { __bf16 h[4]; unsigned long long u; } pk;
            pk.h[0] = (__bf16)v.x; pk.h[1] = (__bf16)v.y;
            pk.h[2] = (__bf16)v.z; pk.h[3] = (__bf16)v.w;
            *reinterpret_cast<unsigned long long*>(&s_rowh[(tid + 256 * i) * 4]) = pk.u;
        }
        if (tid < 32) s_rowh[L_ + tid] = (__bf16)0.0f;
    }

    const int l   = tid & 63;
    const int lr  = l & 15;        // patch within group / W1 A-frag row
    const int lq  = l >> 4;        // k-chunk / C-row quad / sample quad
    const int lkb = lq * 8;

    bf16x8 afrag[4];
    f32x4  b1c[4];
    float  w2x[4][4], w2s[4][4];   // [nb][r] -> hid = nb*16 + lq*4 + r
    #pragma unroll
    for (int nb = 0; nb < 4; ++nb) {
        #pragma unroll
        for (int j = 0; j < 8; ++j) {
            int ks = lkb + j;
            afrag[nb][j] = (__bf16)((ks < PS_) ? W1[(nb * 16 + lr) * PS_ + ks] : 0.0f);
        }
        #pragma unroll
        for (int r = 0; r < 4; ++r) {
            int hid = nb * 16 + lq * 4 + r;
            b1c[nb][r] = b1[hid];
            w2x[nb][r] = W2[hid];
            w2s[nb][r] = W2[HID_ + hid];
        }
    }
    const float b20 = b2[0];
    const float b21 = b2[1];
    const float t0  = (float)lq * (4.0f / 15.0f);
    __syncthreads();

    const int wave = tid >> 6;
    float* obase = out + (size_t)bc * PC_ * PS_;
    const __bf16* bbase = s_rowh + (size_t)(wave * 128 + lr + lq) * 8;

#define MLP_REDUCE(cA0, cA1, cA2, cA3, dxv, dsv)                         \
    {                                                                    \
        float dx0 = 0.0f, dx1 = 0.0f, ds0 = 0.0f, ds1 = 0.0f;            \
        _Pragma("unroll")                                                \
        for (int r = 0; r < 4; ++r) {                                    \
            float g0 = gelu_fast(cA0[r]);                                \
            float g1 = gelu_fast(cA1[r]);                                \
            float g2 = gelu_fast(cA2[r]);                                \
            float g3 = gelu_fast(cA3[r]);                                \
            dx0 = fmaf(g0, w2x[0][r], dx0);                              \
            dx0 = fmaf(g1, w2x[1][r], dx0);                              \
            dx1 = fmaf(g2, w2x[2][r], dx1);                              \
            dx1 = fmaf(g3, w2x[3][r], dx1);                              \
            ds0 = fmaf(g0, w2s[0][r], ds0);                              \
            ds0 = fmaf(g1, w2s[1][r], ds0);                              \
            ds1 = fmaf(g2, w2s[2][r], ds1);                              \
            ds1 = fmaf(g3, w2s[3][r], ds1);                              \
        }                                                                \
        float dx_ = dx0 + dx1, ds_ = ds0 + ds1;                          \
        dx_ += __shfl_xor(dx_, 16, 64);  ds_ += __shfl_xor(ds_, 16, 64); \
        dx_ += __shfl_xor(dx_, 32, 64);  ds_ += __shfl_xor(ds_, 32, 64); \
        dxv = dx_ + b20;  dsv = ds_ + b21;                               \
    }

#define SAMPLE_STORE(p, dxv, dsv)                                        \
    {                                                                    \
        const float refp = (float)((p) * STR_) + 7.5f;                   \
        const float d2   = fmaxf((dsv) + 7.5f, 0.0f);                    \
        const float aa   = (dxv) + refp;                                 \
        const float loi  = fminf(fmaxf(aa - d2, 0.0f), 4095.0f);         \
        const float hii  = fminf(fmaxf(aa + d2, 0.0f), 4095.0f);         \
        const float span = hii - loi;                                    \
        float4 o;                                                        \
        float* ov = reinterpret_cast<float*>(&o);                        \
        _Pragma("unroll")                                                \
        for (int si = 0; si < 4; ++si) {                                 \
            float t  = t0 + (float)si * (1.0f / 15.0f);                  \
            float ix = fmaf(span, t, loi);                               \
            float f  = floorf(ix);                                       \
            float wx = ix - f;                                           \
            int i0 = (int)f;                                             \
            float v0 = (float)s_rowh[i0];                                \
            float v1 = (float)s_rowh[i0 + 1];   /* i0==4095 -> pad, wx==0 */ \
            ov[si] = fmaf(wx, v1 - v0, v0);                              \
        }                                                                \
        if ((p) < PC_)                                                   \
            *reinterpret_cast<float4*>(obase + (size_t)(p) * PS_ + lq * 4) = o; \
    }

    // software-pipelined pairs: prefetch next pair's frags before computing current
    bf16x8 nA = *reinterpret_cast<const bf16x8*>(bbase);
    bf16x8 nB = *reinterpret_cast<const bf16x8*>(bbase + 128);

    #pragma unroll
    for (int i = 0; i < 4; ++i) {
        const bf16x8 cA = nA, cB = nB;
        if (i < 3) {
            nA = *reinterpret_cast<const bf16x8*>(bbase + (2 * i + 2) * 128);
            nB = *reinterpret_cast<const bf16x8*>(bbase + (2 * i + 3) * 128);
        }
        f32x4 a0 = __builtin_amdgcn_mfma_f32_16x16x32_bf16(afrag[0], cA, b1c[0], 0, 0, 0);
        f32x4 a1 = __builtin_amdgcn_mfma_f32_16x16x32_bf16(afrag[1], cA, b1c[1], 0, 0, 0);
        f32x4 a2 = __builtin_amdgcn_mfma_f32_16x16x32_bf16(afrag[2], cA, b1c[2], 0, 0, 0);
        f32x4 a3 = __builtin_amdgcn_mfma_f32_16x16x32_bf16(afrag[3], cA, b1c[3], 0, 0, 0);
        f32x4 q0 = __builtin_amdgcn_mfma_f32_16x16x32_bf16(afrag[0], cB, b1c[0], 0, 0, 0);
        f32x4 q1 = __builtin_amdgcn_mfma_f32_16x16x32_bf16(afrag[1], cB, b1c[1], 0, 0, 0);
        f32x4 q2 = __builtin_amdgcn_mfma_f32_16x16x32_bf16(afrag[2], cB, b1c[2], 0, 0, 0);
        f32x4 q3 = __builtin_amdgcn_mfma_f32_16x16x32_bf16(afrag[3], cB, b1c[3], 0, 0, 0);

        float dxA, dsA, dxB, dsB;
        MLP_REDUCE(a0, a1, a2, a3, dxA, dsA)
        MLP_REDUCE(q0, q1, q2, q3, dxB, dsB)

        const int pA = wave * 128 + (2 * i) * 16 + lr;
        const int pB = pA + 16;
        SAMPLE_STORE(pA, dxA, dsA)
        SAMPLE_STORE(pB, dxB, dsB)
    }
#undef MLP_REDUCE
#undef SAMPLE_STORE
}

extern "C" void kernel_launch(void* const* d_in, const int* in_sizes, int n_in,
                              void* d_out, int out_size, void* d_ws, size_t ws_size,
                              hipStream_t stream) {
    const float* X  = (const float*)d_in[0];
    const float* W1 = (const float*)d_in[1];
    const float* b1 = (const float*)d_in[2];
    const float* W2 = (const float*)d_in[3];
    const float* b2 = (const float*)d_in[4];
    float* out = (float*)d_out;

    depatch_kernel<<<dim3(NBLK_), dim3(256), 0, stream>>>(X, W1, b1, W2, b2, out);
}

// Round 11
// 130.173 us; speedup vs baseline: 1.0476x; 1.0476x over previous
//
#include <hip/hip_runtime.h>
#include <math.h>

#define L_    4096
#define PS_   16
#define STR_  8
#define PC_   511   // (4096-16)/8 + 1
#define HID_  64
#define NBLK_ 2048  // B*C

typedef __bf16 bf16x8 __attribute__((ext_vector_type(8)));
typedef float  f32x4  __attribute__((ext_vector_type(4)));

// gelu tanh-form: x * sigmoid(2c(x + 0.044715 x^3)); |err| <= ~5e-4.
__device__ __forceinline__ float gelu_fast(float x) {
    float u = x * x;
    float t = fmaf(u, 0.10294294f, 2.3022082f);   // 2c·log2(e), pre-scaled
    float a = x * t;
    float e = __builtin_amdgcn_exp2f(a);
    float r = __builtin_amdgcn_rcpf(e + 1.0f);
    return fmaf(-x, r, x);                         // x*(1-r)
}

// read 8 consecutive f32 from LDS, convert to bf16x8 MFMA fragment
__device__ __forceinline__ bf16x8 load_frag(const float* __restrict__ p) {
    float4 v0 = *reinterpret_cast<const float4*>(p);
    float4 v1 = *reinterpret_cast<const float4*>(p + 4);
    bf16x8 r;
    r[0] = (__bf16)v0.x; r[1] = (__bf16)v0.y; r[2] = (__bf16)v0.z; r[3] = (__bf16)v0.w;
    r[4] = (__bf16)v1.x; r[5] = (__bf16)v1.y; r[6] = (__bf16)v1.z; r[7] = (__bf16)v1.w;
    return r;
}

__global__ __launch_bounds__(256, 4) void depatch_kernel(
    const float* __restrict__ X,
    const float* __restrict__ W1,
    const float* __restrict__ b1,
    const float* __restrict__ W2,
    const float* __restrict__ b2,
    float* __restrict__ out)
{
    // single f32 row: sampling (ds_read2_b32 pairs) AND B-frag source (cvt at prefetch).
    // 16.1 KB -> 8 blocks/CU resident (grid-capped max).
    __shared__ __attribute__((aligned(16))) float s_row[L_ + 32];

    const int tid = threadIdx.x;
    const int bc  = blockIdx.x;
    const float* xrow = X + (size_t)bc * L_;

    {
        const float4* src4 = reinterpret_cast<const float4*>(xrow);
        float4* dst4 = reinterpret_cast<float4*>(s_row);
        #pragma unroll
        for (int i = 0; i < 4; ++i) dst4[tid + 256 * i] = src4[tid + 256 * i];
        if (tid < 32) s_row[L_ + tid] = 0.0f;   // pad for tail frag reads + sampling i0+1
    }

    const int l   = tid & 63;
    const int lr  = l & 15;        // patch within group / W1 A-frag row
    const int lq  = l >> 4;        // k-chunk / C-row quad / sample quad
    const int lkb = lq * 8;

    bf16x8 afrag[4];
    f32x4  b1c[4];
    float  w2x[4][4], w2s[4][4];   // [nb][r] -> hid = nb*16 + lq*4 + r
    #pragma unroll
    for (int nb = 0; nb < 4; ++nb) {
        #pragma unroll
        for (int j = 0; j < 8; ++j) {
            int ks = lkb + j;
            afrag[nb][j] = (__bf16)((ks < PS_) ? W1[(nb * 16 + lr) * PS_ + ks] : 0.0f);
        }
        #pragma unroll
        for (int r = 0; r < 4; ++r) {
            int hid = nb * 16 + lq * 4 + r;
            b1c[nb][r] = b1[hid];
            w2x[nb][r] = W2[hid];
            w2s[nb][r] = W2[HID_ + hid];
        }
    }
    const float b20 = b2[0];
    const float b21 = b2[1];
    const float t0  = (float)lq * (4.0f / 15.0f);
    __syncthreads();

    const int wave = tid >> 6;
    float* obase = out + (size_t)bc * PC_ * PS_;
    // group g (0..7): patches pb = wave*128 + g*16; frag floats at (pb+lr+lq)*8 = base + g*128
    const float* bbase = s_row + (size_t)(wave * 128 + lr + lq) * 8;

#define MLP_REDUCE(cA0, cA1, cA2, cA3, dxv, dsv)                         \
    {                                                                    \
        float dx0 = 0.0f, dx1 = 0.0f, ds0 = 0.0f, ds1 = 0.0f;            \
        _Pragma("unroll")                                                \
        for (int r = 0; r < 4; ++r) {                                    \
            float g0 = gelu_fast(cA0[r]);                                \
            float g1 = gelu_fast(cA1[r]);                                \
            float g2 = gelu_fast(cA2[r]);                                \
            float g3 = gelu_fast(cA3[r]);                                \
            dx0 = fmaf(g0, w2x[0][r], dx0);                              \
            dx0 = fmaf(g1, w2x[1][r], dx0);                              \
            dx1 = fmaf(g2, w2x[2][r], dx1);                              \
            dx1 = fmaf(g3, w2x[3][r], dx1);                              \
            ds0 = fmaf(g0, w2s[0][r], ds0);                              \
            ds0 = fmaf(g1, w2s[1][r], ds0);                              \
            ds1 = fmaf(g2, w2s[2][r], ds1);                              \
            ds1 = fmaf(g3, w2s[3][r], ds1);                              \
        }                                                                \
        float dx_ = dx0 + dx1, ds_ = ds0 + ds1;                          \
        dx_ += __shfl_xor(dx_, 16, 64);  ds_ += __shfl_xor(ds_, 16, 64); \
        dx_ += __shfl_xor(dx_, 32, 64);  ds_ += __shfl_xor(ds_, 32, 64); \
        dxv = dx_ + b20;  dsv = ds_ + b21;                               \
    }

#define SAMPLE_STORE(p, dxv, dsv)                                        \
    {                                                                    \
        const float refp = (float)((p) * STR_) + 7.5f;                   \
        const float d2   = fmaxf((dsv) + 7.5f, 0.0f);                    \
        const float aa   = (dxv) + refp;                                 \
        const float loi  = fminf(fmaxf(aa - d2, 0.0f), 4095.0f);         \
        const float hii  = fminf(fmaxf(aa + d2, 0.0f), 4095.0f);         \
        const float span = hii - loi;                                    \
        float4 o;                                                        \
        float* ov = reinterpret_cast<float*>(&o);                        \
        _Pragma("unroll")                                                \
        for (int si = 0; si < 4; ++si) {                                 \
            float t  = t0 + (float)si * (1.0f / 15.0f);                  \
            float ix = fmaf(span, t, loi);                               \
            float f  = floorf(ix);                                       \
            float wx = ix - f;                                           \
            int i0 = (int)f;                                             \
            float v0 = s_row[i0];                                        \
            float v1 = s_row[i0 + 1];   /* i0==4095 -> pad, wx==0 */     \
            ov[si] = fmaf(wx, v1 - v0, v0);                              \
        }                                                                \
        if ((p) < PC_)                                                   \
            *reinterpret_cast<float4*>(obase + (size_t)(p) * PS_ + lq * 4) = o; \
    }

    // software-pipelined pairs: prefetch+convert next pair's frags before computing current
    bf16x8 nA = load_frag(bbase);
    bf16x8 nB = load_frag(bbase + 128);

    #pragma unroll
    for (int i = 0; i < 4; ++i) {
        const bf16x8 cA = nA, cB = nB;
        if (i < 3) {
            nA = load_frag(bbase + (2 * i + 2) * 128);
            nB = load_frag(bbase + (2 * i + 3) * 128);
        }
        f32x4 a0 = __builtin_amdgcn_mfma_f32_16x16x32_bf16(afrag[0], cA, b1c[0], 0, 0, 0);
        f32x4 a1 = __builtin_amdgcn_mfma_f32_16x16x32_bf16(afrag[1], cA, b1c[1], 0, 0, 0);
        f32x4 a2 = __builtin_amdgcn_mfma_f32_16x16x32_bf16(afrag[2], cA, b1c[2], 0, 0, 0);
        f32x4 a3 = __builtin_amdgcn_mfma_f32_16x16x32_bf16(afrag[3], cA, b1c[3], 0, 0, 0);
        f32x4 q0 = __builtin_amdgcn_mfma_f32_16x16x32_bf16(afrag[0], cB, b1c[0], 0, 0, 0);
        f32x4 q1 = __builtin_amdgcn_mfma_f32_16x16x32_bf16(afrag[1], cB, b1c[1], 0, 0, 0);
        f32x4 q2 = __builtin_amdgcn_mfma_f32_16x16x32_bf16(afrag[2], cB, b1c[2], 0, 0, 0);
        f32x4 q3 = __builtin_amdgcn_mfma_f32_16x16x32_bf16(afrag[3], cB, b1c[3], 0, 0, 0);

        float dxA, dsA, dxB, dsB;
        MLP_REDUCE(a0, a1, a2, a3, dxA, dsA)
        MLP_REDUCE(q0, q1, q2, q3, dxB, dsB)

        const int pA = wave * 128 + (2 * i) * 16 + lr;
        const int pB = pA + 16;
        SAMPLE_STORE(pA, dxA, dsA)
        SAMPLE_STORE(pB, dxB, dsB)
    }
#undef MLP_REDUCE
#undef SAMPLE_STORE
}

extern "C" void kernel_launch(void* const* d_in, const int* in_sizes, int n_in,
                              void* d_out, int out_size, void* d_ws, size_t ws_size,
                              hipStream_t stream) {
    const float* X  = (const float*)d_in[0];
    const float* W1 = (const float*)d_in[1];
    const float* b1 = (const float*)d_in[2];
    const float* W2 = (const float*)d_in[3];
    const float* b2 = (const float*)d_in[4];
    float* out = (float*)d_out;

    depatch_kernel<<<dim3(NBLK_), dim3(256), 0, stream>>>(X, W1, b1, W2, b2, out);
}